// Round 12
// baseline (173.026 us; speedup 1.0000x reference)
//
#include <hip/hip_runtime.h>
#include <hip/hip_bf16.h>

typedef __attribute__((ext_vector_type(8))) short s8v;
typedef __attribute__((ext_vector_type(4))) float f4v;
typedef __attribute__((ext_vector_type(16))) float f16v;
typedef __attribute__((ext_vector_type(4))) unsigned short u4v;
typedef __attribute__((ext_vector_type(4))) unsigned int u4i;

#define NH 16

__device__ __forceinline__ unsigned short f2bf(float f) {
  union { float f; unsigned int u; } v; v.f = f;
  unsigned int r = (v.u + 0x7fffu + ((v.u >> 16) & 1u)) >> 16;
  return (unsigned short)r;
}
__device__ __forceinline__ void gll16(const void* g, void* l) {
  __builtin_amdgcn_global_load_lds((const __attribute__((address_space(1))) void*)g,
                                   (__attribute__((address_space(3))) void*)l, 16, 0, 0);
}
__device__ __forceinline__ unsigned int cvtpk(float lo, float hi) {
  unsigned int r;
  asm volatile("v_cvt_pk_bf16_f32 %0, %1, %2" : "=v"(r) : "v"(lo), "v"(hi));
  return r;
}
#define PSWAP(a, b) asm volatile("v_permlane32_swap_b32 %0, %1" : "+v"(a), "+v"(b))

// ---------------- fused prepass:
// z<4: x-transpose  z=4..7: W-transpose  z=8..11: ctx cvt  z=12: lens  z=13: rope tables
__global__ __launch_bounds__(256) void prep_kernel(
    const float* __restrict__ x, const float* __restrict__ ctx,
    const float* __restrict__ Wq, const float* __restrict__ Wk,
    const float* __restrict__ Wv, const float* __restrict__ Wo,
    const int* __restrict__ xm, const int* __restrict__ cm,
    unsigned short* __restrict__ xT, unsigned short* __restrict__ ctxb,
    unsigned short* __restrict__ WqT, unsigned short* __restrict__ WkT,
    unsigned short* __restrict__ WvT, unsigned short* __restrict__ WoT,
    float* __restrict__ lens, float2* __restrict__ rope) {
  const int z = blockIdx.z;
  const int tid = threadIdx.x;
  if (z == 12) {  // mask length reduction (one block)
    if (blockIdx.x | blockIdx.y) return;
    const int w = tid >> 6, lane = tid & 63;
    const int g = w * 2 + (lane >> 5);
    const int l32 = lane & 31;
    const int* m = (g < 4) ? (xm + g * 1024) : (cm + (g - 4) * 1024);
    int s = 0;
    for (int i = l32; i < 1024; i += 32) s += m[i];
    for (int o = 16; o; o >>= 1) s += __shfl_xor(s, o);
    if (l32 == 0) lens[g] = (float)s;
    return;
  }
  if (z == 13) {  // rope cos/sin tables: rope[which][b][t][j] (float2 = cos,sin)
    const int idx = blockIdx.y * 32 + blockIdx.x;
    if (idx >= 256) return;
    const int which = idx >> 7;          // 0 = q, 1 = k
    const int b = (idx >> 5) & 3;
    const int t0 = (idx & 31) * 32;
    const int* m = (which ? cm : xm) + b * 1024;
    const int lane = tid & 63;
    int s = 0;
    for (int i = lane; i < 1024; i += 64) s += m[i];
    for (int o = 32; o; o >>= 1) s += __shfl_xor(s, o);
    const float len = (float)s;
    const int j = tid & 31;
    const float theta = 10.0f * __expf((float)j * -0.28782313662425572f);  // 10*10000^(-j/32)
    float2* rt = rope + ((size_t)(which * 4 + b) << 15);
    for (int it = 0; it < 4; ++it) {
      const int t = t0 + (tid >> 5) + it * 8;
      const float fr = (float)t / len * theta;
      float sn, cs;
      __sincosf(fr, &sn, &cs);
      rt[t * 32 + j] = make_float2(cs, sn);
    }
    return;
  }
  if (z >= 8) {  // ctx f32 -> bf16, batch z-8
    const float* in = ctx + ((size_t)(z - 8) << 20);
    unsigned short* out = ctxb + ((size_t)(z - 8) << 20);
    const int i = (blockIdx.y * 32 + blockIdx.x) * 1024 + tid * 4;
    const f4v v = *(const f4v*)&in[i];
    u4v o;
#pragma unroll
    for (int j = 0; j < 4; ++j) o[j] = f2bf(v[j]);
    *(u4v*)&out[i] = o;
    return;
  }
  __shared__ unsigned short tile[32][33];
  const float* in;
  unsigned short* out;
  if (z < 4)      { in = x + ((size_t)z << 20); out = xT + ((size_t)z << 20); }
  else if (z == 4){ in = Wq; out = WqT; }
  else if (z == 5){ in = Wk; out = WkT; }
  else if (z == 6){ in = Wv; out = WvT; }
  else            { in = Wo; out = WoT; }
  const int r0 = blockIdx.y * 32, c0 = blockIdx.x * 32;
  const int tx = tid & 31, ty = tid >> 5;
  for (int i = ty; i < 32; i += 8) tile[i][tx] = f2bf(in[(size_t)(r0 + i) * 1024 + c0 + tx]);
  __syncthreads();
  for (int i = ty; i < 32; i += 8) out[(size_t)(c0 + i) * 1024 + r0 + tx] = tile[tx][i];
}

// stage one 128x64 K-tile pair (A and B) into LDS buffer `buf`
#define STAGE_QKV(buf, kt_) do {                                         \
    const int kn_ = (kt_) * 64;                                          \
    _Pragma("unroll")                                                    \
    for (int i_ = 0; i_ < 4; ++i_) {                                     \
      gll16(Ap + i_ * 32 * 1024 + kn_, &As[buf][(i_ * 256 + tid) * 8]);  \
      gll16(Bp + i_ * 32 * 1024 + kn_, &Bs[buf][(i_ * 256 + tid) * 8]);  \
    }                                                                    \
  } while (0)

// ---------------- fused QKV projection GEMM; mode 0: Q(+RoPE, pre-scaled), 1: K(+RoPE), 2: V^T
// counted-vmcnt pipeline: 2 tiles in flight, never drain to 0 in the loop (T4).
// Fully-masked 128-row m-blocks are skipped (consumers never read them).
__global__ __launch_bounds__(256) void gemm_qkv_kernel(
    const unsigned short* __restrict__ xT, const unsigned short* __restrict__ ctxb,
    const unsigned short* __restrict__ WqT, const unsigned short* __restrict__ WkT,
    const unsigned short* __restrict__ WvT,
    const float* __restrict__ bq, const float* __restrict__ bk, const float* __restrict__ bv,
    unsigned short* __restrict__ Qb, unsigned short* __restrict__ Kb,
    unsigned short* __restrict__ Vtb, const float2* __restrict__ rope,
    const float* __restrict__ lens) {
  __shared__ __attribute__((aligned(16))) unsigned short As[2][8192];
  __shared__ __attribute__((aligned(16))) unsigned short Bs[2][8192];
  const int id = blockIdx.x + (blockIdx.y << 3) + (blockIdx.z << 8);  // 0..767
  const int rest = id >> 3;
  const int my = (id & 7) + ((rest & 3) << 3);  // m-block 0..31  (id%8 == my%8)
  const int nx = (rest >> 2) & 7;               // n-block 0..7
  const int mode = rest >> 5;                   // 0..2
  const int b = my >> 3;
  const int lim = (int)lens[(mode == 0 ? 0 : 4) + b];
  if (((my & 7) << 7) >= lim) return;
  const unsigned short* A  = (mode == 0) ? xT : ctxb;
  const unsigned short* Bt = (mode == 0) ? WqT : (mode == 1) ? WkT : WvT;
  const float* bias        = (mode == 0) ? bq : (mode == 1) ? bk : bv;
  const int tid = threadIdx.x;
  const int lane = tid & 63, w = tid >> 6;
  const int lq = lane & 15, lg = lane >> 4;
  const int m0 = my * 128, n0 = nx * 128;
  const int wm = (w & 1) * 64, wn = (w >> 1) * 64;
  const int cswz = (lq & 7) << 3;
  const int srow = tid >> 3;
  const int scol = ((tid & 7) * 8) ^ ((srow & 7) << 3);
  const unsigned short* Ap = A + (size_t)(m0 + srow) * 1024 + scol;
  const unsigned short* Bp = Bt + (size_t)(n0 + srow) * 1024 + scol;
  f4v acc[4][4] = {};

  STAGE_QKV(0, 0);
  STAGE_QKV(1, 1);

  for (int kt = 0; kt < 16; ++kt) {
    const int cur = kt & 1;
    if (kt < 15) {
      asm volatile("s_waitcnt vmcnt(8)" ::: "memory");
    } else {
      asm volatile("s_waitcnt vmcnt(0)" ::: "memory");
    }
    __builtin_amdgcn_s_barrier();
#pragma unroll
    for (int kc = 0; kc < 2; ++kc) {
      s8v af[4], bfr[4];
#pragma unroll
      for (int i = 0; i < 4; ++i)
        af[i] = *(const s8v*)&As[cur][(wm + i * 16 + lq) * 64 + ((kc * 32 + lg * 8) ^ cswz)];
#pragma unroll
      for (int i = 0; i < 4; ++i)
        bfr[i] = *(const s8v*)&Bs[cur][(wn + i * 16 + lq) * 64 + ((kc * 32 + lg * 8) ^ cswz)];
#pragma unroll
      for (int mi = 0; mi < 4; ++mi)
#pragma unroll
        for (int ni = 0; ni < 4; ++ni)
          acc[mi][ni] = __builtin_amdgcn_mfma_f32_16x16x32_bf16(af[mi], bfr[ni], acc[mi][ni], 0, 0, 0);
    }
    __builtin_amdgcn_s_barrier();
    if (kt + 2 < 16) STAGE_QKV(cur, kt + 2);
  }

  float bv4[4];
#pragma unroll
  for (int ni = 0; ni < 4; ++ni) bv4[ni] = bias[n0 + wn + ni * 16 + lq];

  if (mode <= 1) {
    unsigned short* O = mode ? Kb : Qb;
    const float osc = mode ? 1.0f : 0.0450842200277f;  // log2(e)/32 folded into Q
    const float2* rt = rope + ((size_t)(mode * 4 + b) << 15);
    const int h = (n0 + wn) >> 6;
#pragma unroll
    for (int mi = 0; mi < 4; ++mi) {
#pragma unroll
      for (int rr = 0; rr < 4; ++rr) {
        const int m = m0 + wm + mi * 16 + lg * 4 + rr;
        const int t = m & 1023;
#pragma unroll
        for (int ni = 0; ni < 2; ++ni) {
          const int jj = ni * 16 + lq;
          const float2 cs2 = rt[t * 32 + jj];
          const float x1 = acc[mi][ni][rr] + bv4[ni];
          const float x2 = acc[mi][ni + 2][rr] + bv4[ni + 2];
          unsigned short* bp = &O[((size_t)((b * NH + h) * 1024 + t)) * 64 + jj];
          bp[0] = f2bf((x1 * cs2.x - x2 * cs2.y) * osc);
          bp[32] = f2bf((x1 * cs2.y + x2 * cs2.x) * osc);
        }
      }
    }
  } else {
#pragma unroll
    for (int mi = 0; mi < 4; ++mi) {
      const int mbase = m0 + wm + mi * 16 + lg * 4;
      const int l0 = mbase & 1023;
#pragma unroll
      for (int ni = 0; ni < 4; ++ni) {
        const int n = n0 + wn + ni * 16 + lq;
        const int hh = n >> 6, d = n & 63;
        u4v pk;
#pragma unroll
        for (int rr = 0; rr < 4; ++rr) pk[rr] = f2bf(acc[mi][ni][rr] + bv4[ni]);
        *(u4v*)&Vtb[((size_t)((b * NH + hh) * 64 + d)) * 1024 + l0] = pk;
      }
    }
  }
}

// ---------------- output GEMM: AOb (4096x1024) @ WoT -> out f32 (B,N,T) + query mask
__global__ __launch_bounds__(256) void gemm_o_kernel(
    const unsigned short* __restrict__ A, const unsigned short* __restrict__ Bt,
    const float* __restrict__ bias, float* __restrict__ Cout,
    const int* __restrict__ xmask, const float* __restrict__ lens) {
  __shared__ __attribute__((aligned(16))) unsigned short As[2][8192];
  __shared__ __attribute__((aligned(16))) unsigned short Bs[2][8192];
  const int id = blockIdx.x + (blockIdx.y << 3);  // 0..255
  const int rest = id >> 3;
  const int my = (id & 7) + ((rest & 3) << 3);    // m-block 0..31
  const int nx = rest >> 2;                       // n-block 0..7
  const int tid = threadIdx.x;
  const int lane = tid & 63, w = tid >> 6;
  const int lq = lane & 15, lg = lane >> 4;
  const int m0 = my * 128, n0 = nx * 128;
  const int wm = (w & 1) * 64, wn = (w >> 1) * 64;
  const int b = my >> 3;

  if (((my & 7) << 7) >= (int)lens[b]) {
#pragma unroll
    for (int mi = 0; mi < 4; ++mi) {
      const int t0 = (m0 + wm + mi * 16 + lg * 4) & 1023;
      const f4v z = {};
#pragma unroll
      for (int ni = 0; ni < 4; ++ni) {
        const int n = n0 + wn + ni * 16 + lq;
        *(f4v*)&Cout[(size_t)b * 1024 * 1024 + (size_t)n * 1024 + t0] = z;
      }
    }
    return;
  }

  const int cswz = (lq & 7) << 3;
  const int srow = tid >> 3;
  const int scol = ((tid & 7) * 8) ^ ((srow & 7) << 3);
  const unsigned short* Ap = A + (size_t)(m0 + srow) * 1024 + scol;
  const unsigned short* Bp = Bt + (size_t)(n0 + srow) * 1024 + scol;
  f4v acc[4][4] = {};

  STAGE_QKV(0, 0);
  STAGE_QKV(1, 1);

  for (int kt = 0; kt < 16; ++kt) {
    const int cur = kt & 1;
    if (kt < 15) {
      asm volatile("s_waitcnt vmcnt(8)" ::: "memory");
    } else {
      asm volatile("s_waitcnt vmcnt(0)" ::: "memory");
    }
    __builtin_amdgcn_s_barrier();
#pragma unroll
    for (int kc = 0; kc < 2; ++kc) {
      s8v af[4], bfr[4];
#pragma unroll
      for (int i = 0; i < 4; ++i)
        af[i] = *(const s8v*)&As[cur][(wm + i * 16 + lq) * 64 + ((kc * 32 + lg * 8) ^ cswz)];
#pragma unroll
      for (int i = 0; i < 4; ++i)
        bfr[i] = *(const s8v*)&Bs[cur][(wn + i * 16 + lq) * 64 + ((kc * 32 + lg * 8) ^ cswz)];
#pragma unroll
      for (int mi = 0; mi < 4; ++mi)
#pragma unroll
        for (int ni = 0; ni < 4; ++ni)
          acc[mi][ni] = __builtin_amdgcn_mfma_f32_16x16x32_bf16(af[mi], bfr[ni], acc[mi][ni], 0, 0, 0);
    }
    __builtin_amdgcn_s_barrier();
    if (kt + 2 < 16) STAGE_QKV(cur, kt + 2);
  }

  float bv4[4];
#pragma unroll
  for (int ni = 0; ni < 4; ++ni) bv4[ni] = bias[n0 + wn + ni * 16 + lq];
#pragma unroll
  for (int mi = 0; mi < 4; ++mi) {
    const int mbase = m0 + wm + mi * 16 + lg * 4;
    const int t0 = mbase & 1023;
#pragma unroll
    for (int ni = 0; ni < 4; ++ni) {
      const int n = n0 + wn + ni * 16 + lq;
      f4v pk;
#pragma unroll
      for (int rr = 0; rr < 4; ++rr) {
        float v = acc[mi][ni][rr] + bv4[ni];
        v *= (float)xmask[b * 1024 + t0 + rr];
        pk[rr] = v;
      }
      *(f4v*)&Cout[(size_t)b * 1024 * 1024 + (size_t)n * 1024 + t0] = pk;
    }
  }
}

// ---------------- flash attention; 4 waves x 32 q-rows, 32x32x16 MFMA, in-register softmax.
// Swapped QK (mfma(K,Q)): lane holds all 64 tile-keys for q-row (lane&31) in s0/s1 regs.
// P -> bf16 A-frags via v_cvt_pk_bf16_f32 + v_permlane32_swap_b32 (no LDS P-bounce).
#define ASTAGE(buf, kt_) do {                                            \
    const int kn_ = (kt_) * 64;                                          \
    gll16(&Kp[(size_t)(kn_ + sr) * 64 + scx], &Ks[buf][tid * 8]);        \
    gll16(&Kp[(size_t)(kn_ + sr + 32) * 64 + scx], &Ks[buf][2048 + tid * 8]); \
    gll16(&Vp[(size_t)sr * 1024 + kn_ + scx], &Vs[buf][tid * 8]);        \
    gll16(&Vp[(size_t)(sr + 32) * 1024 + kn_ + scx], &Vs[buf][2048 + tid * 8]); \
  } while (0)

__global__ __launch_bounds__(256) void attn_kernel(
    const unsigned short* __restrict__ Q, const unsigned short* __restrict__ K,
    const unsigned short* __restrict__ Vt, const float* __restrict__ lens,
    unsigned short* __restrict__ Aout) {
  __shared__ __attribute__((aligned(16))) unsigned short Ks[2][4096];
  __shared__ __attribute__((aligned(16))) unsigned short Vs[2][4096];
  __shared__ float Ls[4][32];
  const int tid = threadIdx.x;
  const int lane = tid & 63, w = tid >> 6;
  const int l31 = lane & 31, hi = lane >> 5;
  const int hi4 = hi * 4, hi8 = hi * 8;
  const int cswz = (l31 & 7) << 3;
  // XCD swizzle: the 8 q-blocks sharing one (b,h) K/V panel land on the same XCD
  const int id = blockIdx.x + (blockIdx.y << 3);  // 0..511
  const int bh = (id & 7) + (((id >> 3) & 7) << 3);
  const int qblk = id >> 6;
  const int b = bh >> 4, h = bh & 15;
  const int lenq = (int)lens[b];
  if (qblk * 128 >= lenq) return;
  const int lenk = (int)lens[4 + b];
  const int nkt = (lenk + 63) >> 6;
  const int qrow0 = qblk * 128 + w * 32;
  const unsigned short* Qp = Q + ((size_t)bh * 1024 + qrow0) * 64;
  const unsigned short* Kp = K + (size_t)bh * 65536;
  const unsigned short* Vp = Vt + (size_t)bh * 65536;
  s8v Qf[4];
#pragma unroll
  for (int ks = 0; ks < 4; ++ks)
    Qf[ks] = *(const s8v*)&Qp[l31 * 64 + ks * 16 + hi8];
  const int sr = tid >> 3;
  const int scx = ((tid & 7) * 8) ^ ((sr & 7) << 3);

  ASTAGE(0, 0);
  __syncthreads();

  float m_run = -1e30f, s_run = 0.0f;
  f16v acc0 = {}, acc1 = {};
  for (int kt = 0; kt < nkt; ++kt) {
    const int p = kt & 1;
    if (kt + 1 < nkt) ASTAGE(p ^ 1, kt + 1);
    const int k0 = kt * 64;
    const bool full = (k0 + 64 <= lenk);
    f16v s0 = {}, s1 = {};
    __builtin_amdgcn_s_setprio(1);
#pragma unroll
    for (int ks = 0; ks < 4; ++ks) {
      const int c = (ks * 16 + hi8) ^ cswz;
      const s8v kf0 = *(const s8v*)&Ks[p][l31 * 64 + c];
      const s8v kf1 = *(const s8v*)&Ks[p][(32 + l31) * 64 + c];
      s0 = __builtin_amdgcn_mfma_f32_32x32x16_bf16(kf0, Qf[ks], s0, 0, 0, 0);
      s1 = __builtin_amdgcn_mfma_f32_32x32x16_bf16(kf1, Qf[ks], s1, 0, 0, 0);
    }
    __builtin_amdgcn_s_setprio(0);
    float tmax = -1e30f;
#pragma unroll
    for (int r = 0; r < 16; ++r) {
      if (!full) {
        const int kr = k0 + (r & 3) + 8 * (r >> 2) + hi4;
        if (kr >= lenk) s0[r] = -1e30f;
        if (kr + 32 >= lenk) s1[r] = -1e30f;
      }
      tmax = fmaxf(tmax, fmaxf(s0[r], s1[r]));
    }
    tmax = fmaxf(tmax, __shfl_xor(tmax, 32));
    if (__any(tmax > m_run + 8.0f)) {  // T13 defer-max
      const float m_new = fmaxf(m_run, tmax);
      const float alpha = exp2f(m_run - m_new);
      s_run *= alpha;
      m_run = m_new;
      if (hi == 0) Ls[w][l31] = alpha;
      asm volatile("s_waitcnt lgkmcnt(0)" ::: "memory");
#pragma unroll
      for (int r = 0; r < 16; ++r) {
        const float a = Ls[w][(r & 3) + 8 * (r >> 2) + hi4];
        acc0[r] *= a;
        acc1[r] *= a;
      }
    }
    float psum = 0.0f;
    float e0v[16], e1v[16];
#pragma unroll
    for (int r = 0; r < 16; ++r) {
      e0v[r] = exp2f(s0[r] - m_run);
      e1v[r] = exp2f(s1[r] - m_run);
      psum += e0v[r] + e1v[r];
    }
    psum += __shfl_xor(psum, 32);
    s_run += psum;
    // P fragments: swap(cvtpk(e2i,e2i+1), cvtpk(e2i+4,e2i+5)) -> frag words 0/2 etc.
    s8v pf[4];
    {
      unsigned a0 = cvtpk(e0v[0], e0v[1]),   b0 = cvtpk(e0v[4], e0v[5]);
      unsigned a1 = cvtpk(e0v[2], e0v[3]),   b1 = cvtpk(e0v[6], e0v[7]);
      unsigned a2 = cvtpk(e0v[8], e0v[9]),   b2 = cvtpk(e0v[12], e0v[13]);
      unsigned a3 = cvtpk(e0v[10], e0v[11]), b3 = cvtpk(e0v[14], e0v[15]);
      PSWAP(a0, b0); PSWAP(a1, b1); PSWAP(a2, b2); PSWAP(a3, b3);
      u4i t0 = {a0, a1, b0, b1}; pf[0] = *(s8v*)&t0;
      u4i t1 = {a2, a3, b2, b3}; pf[1] = *(s8v*)&t1;
      unsigned c0 = cvtpk(e1v[0], e1v[1]),   d0 = cvtpk(e1v[4], e1v[5]);
      unsigned c1 = cvtpk(e1v[2], e1v[3]),   d1 = cvtpk(e1v[6], e1v[7]);
      unsigned c2 = cvtpk(e1v[8], e1v[9]),   d2 = cvtpk(e1v[12], e1v[13]);
      unsigned c3 = cvtpk(e1v[10], e1v[11]), d3 = cvtpk(e1v[14], e1v[15]);
      PSWAP(c0, d0); PSWAP(c1, d1); PSWAP(c2, d2); PSWAP(c3, d3);
      u4i t2 = {c0, c1, d0, d1}; pf[2] = *(s8v*)&t2;
      u4i t3 = {c2, c3, d2, d3}; pf[3] = *(s8v*)&t3;
    }
    __builtin_amdgcn_s_setprio(1);
#pragma unroll
    for (int st = 0; st < 4; ++st) {
      const int c = (st * 16 + hi8) ^ cswz;
      const s8v vf0 = *(const s8v*)&Vs[p][l31 * 64 + c];
      const s8v vf1 = *(const s8v*)&Vs[p][(32 + l31) * 64 + c];
      acc0 = __builtin_amdgcn_mfma_f32_32x32x16_bf16(pf[st], vf0, acc0, 0, 0, 0);
      acc1 = __builtin_amdgcn_mfma_f32_32x32x16_bf16(pf[st], vf1, acc1, 0, 0, 0);
    }
    __builtin_amdgcn_s_setprio(0);
    if (kt + 1 < nkt) __syncthreads();
  }
  const float inv = 1.0f / s_run;
  if (hi == 0) Ls[w][l31] = inv;
  asm volatile("s_waitcnt lgkmcnt(0)" ::: "memory");
#pragma unroll
  for (int r = 0; r < 16; ++r) {
    const int cr = (r & 3) + 8 * (r >> 2) + hi4;
    const float iv = Ls[w][cr];
    unsigned short* op = Aout + ((size_t)(b * 1024 + qrow0 + cr)) * 1024 + h * 64;
    op[l31] = f2bf(acc0[r] * iv);
    op[32 + l31] = f2bf(acc1[r] * iv);
  }
}

extern "C" void kernel_launch(void* const* d_in, const int* in_sizes, int n_in,
                              void* d_out, int out_size, void* d_ws, size_t ws_size,
                              hipStream_t stream) {
  const float* x   = (const float*)d_in[0];
  const float* ctx = (const float*)d_in[1];
  const int* xm = (const int*)d_in[2];
  const int* cm = (const int*)d_in[3];
  const float* Wq = (const float*)d_in[4];
  const float* bq = (const float*)d_in[5];
  const float* Wk = (const float*)d_in[6];
  const float* bk = (const float*)d_in[7];
  const float* Wv = (const float*)d_in[8];
  const float* bv = (const float*)d_in[9];
  const float* Wo = (const float*)d_in[10];
  const float* bo = (const float*)d_in[11];

  char* ws = (char*)d_ws;
  const size_t MB = 1024 * 1024;
  unsigned short* xT   = (unsigned short*)(ws);           // 8 MB
  unsigned short* AOb  = (unsigned short*)(ws);           // 8 MB (alias)
  unsigned short* ctxb = (unsigned short*)(ws + 8 * MB);  // 8 MB
  unsigned short* WqT  = (unsigned short*)(ws + 16 * MB); // 2 MB
  unsigned short* WkT  = (unsigned short*)(ws + 18 * MB); // 2 MB
  unsigned short* WvT  = (unsigned short*)(ws + 20 * MB); // 2 MB
  unsigned short* WoT  = (unsigned short*)(ws + 22 * MB); // 2 MB
  unsigned short* Qb   = (unsigned short*)(ws + 24 * MB); // 8 MB
  unsigned short* Kb   = (unsigned short*)(ws + 32 * MB); // 8 MB
  unsigned short* Vtb  = (unsigned short*)(ws + 40 * MB); // 8 MB
  float* lens          = (float*)(ws + 48 * MB);          // 32 B
  float2* rope         = (float2*)(ws + 49 * MB);         // 2 MB

  prep_kernel<<<dim3(32, 32, 14), 256, 0, stream>>>(x, ctx, Wq, Wk, Wv, Wo, xm, cm,
                                                    xT, ctxb, WqT, WkT, WvT, WoT, lens, rope);
  gemm_qkv_kernel<<<dim3(8, 32, 3), 256, 0, stream>>>(xT, ctxb, WqT, WkT, WvT,
                                                      bq, bk, bv, Qb, Kb, Vtb, rope, lens);
  attn_kernel<<<dim3(8, 64), 256, 0, stream>>>(Qb, Kb, Vtb, lens, AOb);
  gemm_o_kernel<<<dim3(8, 32), 256, 0, stream>>>(AOb, WoT, bo, (float*)d_out, xm, lens);
}

// Round 13
// 118.345 us; speedup vs baseline: 1.4621x; 1.4621x over previous
//
#include <hip/hip_runtime.h>
#include <hip/hip_bf16.h>

typedef __attribute__((ext_vector_type(8))) short s8v;
typedef __attribute__((ext_vector_type(4))) float f4v;
typedef __attribute__((ext_vector_type(4))) unsigned short u4v;
typedef __attribute__((ext_vector_type(2))) unsigned int u2v;

#define NH 16

__device__ __forceinline__ unsigned short f2bf(float f) {
  union { float f; unsigned int u; } v; v.f = f;
  unsigned int r = (v.u + 0x7fffu + ((v.u >> 16) & 1u)) >> 16;
  return (unsigned short)r;
}
__device__ __forceinline__ void gll16(const void* g, void* l) {
  __builtin_amdgcn_global_load_lds((const __attribute__((address_space(1))) void*)g,
                                   (__attribute__((address_space(3))) void*)l, 16, 0, 0);
}
__device__ __forceinline__ unsigned int cvtpk(float lo, float hi) {
  unsigned int r;
  asm volatile("v_cvt_pk_bf16_f32 %0, %1, %2" : "=v"(r) : "v"(lo), "v"(hi));
  return r;
}

// ---------------- fused prepass:
// z<4: x-transpose  z=4..7: W-transpose  z=8..11: ctx cvt  z=12: lens  z=13: rope tables
__global__ __launch_bounds__(256) void prep_kernel(
    const float* __restrict__ x, const float* __restrict__ ctx,
    const float* __restrict__ Wq, const float* __restrict__ Wk,
    const float* __restrict__ Wv, const float* __restrict__ Wo,
    const int* __restrict__ xm, const int* __restrict__ cm,
    unsigned short* __restrict__ xT, unsigned short* __restrict__ ctxb,
    unsigned short* __restrict__ WqT, unsigned short* __restrict__ WkT,
    unsigned short* __restrict__ WvT, unsigned short* __restrict__ WoT,
    float* __restrict__ lens, float2* __restrict__ rope) {
  const int z = blockIdx.z;
  const int tid = threadIdx.x;
  if (z == 12) {  // mask length reduction (one block)
    if (blockIdx.x | blockIdx.y) return;
    const int w = tid >> 6, lane = tid & 63;
    const int g = w * 2 + (lane >> 5);
    const int l32 = lane & 31;
    const int* m = (g < 4) ? (xm + g * 1024) : (cm + (g - 4) * 1024);
    int s = 0;
    for (int i = l32; i < 1024; i += 32) s += m[i];
    for (int o = 16; o; o >>= 1) s += __shfl_xor(s, o);
    if (l32 == 0) lens[g] = (float)s;
    return;
  }
  if (z == 13) {  // rope cos/sin tables: rope[which][b][t][j] (float2 = cos,sin)
    const int idx = blockIdx.y * 32 + blockIdx.x;
    if (idx >= 256) return;
    const int which = idx >> 7;          // 0 = q, 1 = k
    const int b = (idx >> 5) & 3;
    const int t0 = (idx & 31) * 32;
    const int* m = (which ? cm : xm) + b * 1024;
    const int lane = tid & 63;
    int s = 0;
    for (int i = lane; i < 1024; i += 64) s += m[i];
    for (int o = 32; o; o >>= 1) s += __shfl_xor(s, o);
    const float len = (float)s;
    const int j = tid & 31;
    const float theta = 10.0f * __expf((float)j * -0.28782313662425572f);  // 10*10000^(-j/32)
    float2* rt = rope + ((size_t)(which * 4 + b) << 15);
    for (int it = 0; it < 4; ++it) {
      const int t = t0 + (tid >> 5) + it * 8;
      const float fr = (float)t / len * theta;
      float sn, cs;
      __sincosf(fr, &sn, &cs);
      rt[t * 32 + j] = make_float2(cs, sn);
    }
    return;
  }
  if (z >= 8) {  // ctx f32 -> bf16, batch z-8
    const float* in = ctx + ((size_t)(z - 8) << 20);
    unsigned short* out = ctxb + ((size_t)(z - 8) << 20);
    const int i = (blockIdx.y * 32 + blockIdx.x) * 1024 + tid * 4;
    const f4v v = *(const f4v*)&in[i];
    u4v o;
#pragma unroll
    for (int j = 0; j < 4; ++j) o[j] = f2bf(v[j]);
    *(u4v*)&out[i] = o;
    return;
  }
  __shared__ unsigned short tile[32][33];
  const float* in;
  unsigned short* out;
  if (z < 4)      { in = x + ((size_t)z << 20); out = xT + ((size_t)z << 20); }
  else if (z == 4){ in = Wq; out = WqT; }
  else if (z == 5){ in = Wk; out = WkT; }
  else if (z == 6){ in = Wv; out = WvT; }
  else            { in = Wo; out = WoT; }
  const int r0 = blockIdx.y * 32, c0 = blockIdx.x * 32;
  const int tx = tid & 31, ty = tid >> 5;
  for (int i = ty; i < 32; i += 8) tile[i][tx] = f2bf(in[(size_t)(r0 + i) * 1024 + c0 + tx]);
  __syncthreads();
  for (int i = ty; i < 32; i += 8) out[(size_t)(c0 + i) * 1024 + r0 + tx] = tile[tx][i];
}

// stage one 128x32 K-tile pair (A and B) into LDS buffer `buf` (BK=32, 4 loads/thread)
#define STAGE_G(buf, kt_) do {                                           \
    const int kn_ = (kt_) * 32;                                          \
    _Pragma("unroll")                                                    \
    for (int i_ = 0; i_ < 2; ++i_) {                                     \
      gll16(Ap + i_ * 64 * 1024 + kn_, &As[buf][(i_ * 256 + tid) * 8]);  \
      gll16(Bp + i_ * 64 * 1024 + kn_, &Bs[buf][(i_ * 256 + tid) * 8]);  \
    }                                                                    \
  } while (0)

// ---------------- fused QKV projection GEMM; mode 0: Q(+RoPE, pre-scaled), 1: K(+RoPE), 2: V^T
// BK=32 double-buffer (32 KB LDS -> 3 blocks/CU), counted vmcnt: never drain to 0 in-loop.
__global__ __launch_bounds__(256) void gemm_qkv_kernel(
    const unsigned short* __restrict__ xT, const unsigned short* __restrict__ ctxb,
    const unsigned short* __restrict__ WqT, const unsigned short* __restrict__ WkT,
    const unsigned short* __restrict__ WvT,
    const float* __restrict__ bq, const float* __restrict__ bk, const float* __restrict__ bv,
    unsigned short* __restrict__ Qb, unsigned short* __restrict__ Kb,
    unsigned short* __restrict__ Vtb, const float2* __restrict__ rope,
    const float* __restrict__ lens) {
  __shared__ __attribute__((aligned(16))) unsigned short As[2][4096];
  __shared__ __attribute__((aligned(16))) unsigned short Bs[2][4096];
  const int id = blockIdx.x + (blockIdx.y << 3) + (blockIdx.z << 8);  // 0..767
  const int rest = id >> 3;
  const int my = (id & 7) + ((rest & 3) << 3);  // m-block 0..31  (id%8 == my%8)
  const int nx = (rest >> 2) & 7;               // n-block 0..7
  const int mode = rest >> 5;                   // 0..2
  const int b = my >> 3;
  const int lim = (int)lens[(mode == 0 ? 0 : 4) + b];
  if (((my & 7) << 7) >= lim) return;           // fully-masked m-block: consumers never read it
  const unsigned short* A  = (mode == 0) ? xT : ctxb;
  const unsigned short* Bt = (mode == 0) ? WqT : (mode == 1) ? WkT : WvT;
  const float* bias        = (mode == 0) ? bq : (mode == 1) ? bk : bv;
  const int tid = threadIdx.x;
  const int lane = tid & 63, w = tid >> 6;
  const int lq = lane & 15, lg = lane >> 4;
  const int m0 = my * 128, n0 = nx * 128;
  const int wm = (w & 1) * 64, wn = (w >> 1) * 64;
  const int srow = tid >> 2;                       // 0..63 (+64 for second half)
  const int scol = ((tid & 3) * 8) ^ ((srow & 3) << 3);
  const unsigned short* Ap = A + (size_t)(m0 + srow) * 1024 + scol;
  const unsigned short* Bp = Bt + (size_t)(n0 + srow) * 1024 + scol;
  const int rc = (lg * 8) ^ ((lq & 3) << 3);       // read col, matches write swizzle
  f4v acc[4][4] = {};

  STAGE_G(0, 0);
  STAGE_G(1, 1);

  for (int kt = 0; kt < 32; ++kt) {
    const int cur = kt & 1;
    if (kt < 31) {
      asm volatile("s_waitcnt vmcnt(4)" ::: "memory");  // tile kt landed; kt+1 stays in flight
    } else {
      asm volatile("s_waitcnt vmcnt(0)" ::: "memory");
    }
    __builtin_amdgcn_s_barrier();   // raw barrier: no implicit vmcnt(0) drain
    s8v af[4], bfr[4];
#pragma unroll
    for (int i = 0; i < 4; ++i)
      af[i] = *(const s8v*)&As[cur][(wm + i * 16 + lq) * 32 + rc];
#pragma unroll
    for (int i = 0; i < 4; ++i)
      bfr[i] = *(const s8v*)&Bs[cur][(wn + i * 16 + lq) * 32 + rc];
#pragma unroll
    for (int mi = 0; mi < 4; ++mi)
#pragma unroll
      for (int ni = 0; ni < 4; ++ni)
        acc[mi][ni] = __builtin_amdgcn_mfma_f32_16x16x32_bf16(af[mi], bfr[ni], acc[mi][ni], 0, 0, 0);
    __builtin_amdgcn_s_barrier();   // all waves done reading buf[cur] before overwrite
    if (kt + 2 < 32) STAGE_G(cur, kt + 2);
  }

  float bv4[4];
#pragma unroll
  for (int ni = 0; ni < 4; ++ni) bv4[ni] = bias[n0 + wn + ni * 16 + lq];

  if (mode <= 1) {
    unsigned short* O = mode ? Kb : Qb;
    const float osc = mode ? 1.0f : 0.0450842200277f;  // log2(e)/32 folded into Q
    const float2* rt = rope + ((size_t)(mode * 4 + b) << 15);
    const int h = (n0 + wn) >> 6;
#pragma unroll
    for (int mi = 0; mi < 4; ++mi) {
#pragma unroll
      for (int rr = 0; rr < 4; ++rr) {
        const int m = m0 + wm + mi * 16 + lg * 4 + rr;
        const int t = m & 1023;
#pragma unroll
        for (int ni = 0; ni < 2; ++ni) {
          const int jj = ni * 16 + lq;
          const float2 cs2 = rt[t * 32 + jj];
          const float x1 = acc[mi][ni][rr] + bv4[ni];
          const float x2 = acc[mi][ni + 2][rr] + bv4[ni + 2];
          unsigned short* bp = &O[((size_t)((b * NH + h) * 1024 + t)) * 64 + jj];
          bp[0] = f2bf((x1 * cs2.x - x2 * cs2.y) * osc);
          bp[32] = f2bf((x1 * cs2.y + x2 * cs2.x) * osc);
        }
      }
    }
  } else {
#pragma unroll
    for (int mi = 0; mi < 4; ++mi) {
      const int mbase = m0 + wm + mi * 16 + lg * 4;
      const int l0 = mbase & 1023;
#pragma unroll
      for (int ni = 0; ni < 4; ++ni) {
        const int n = n0 + wn + ni * 16 + lq;
        const int hh = n >> 6, d = n & 63;
        u4v pk;
#pragma unroll
        for (int rr = 0; rr < 4; ++rr) pk[rr] = f2bf(acc[mi][ni][rr] + bv4[ni]);
        *(u4v*)&Vtb[((size_t)((b * NH + hh) * 64 + d)) * 1024 + l0] = pk;
      }
    }
  }
}

// ---------------- output GEMM: AOb (4096x1024) @ WoT -> out f32 (B,N,T) + query mask
__global__ __launch_bounds__(256) void gemm_o_kernel(
    const unsigned short* __restrict__ A, const unsigned short* __restrict__ Bt,
    const float* __restrict__ bias, float* __restrict__ Cout,
    const int* __restrict__ xmask, const float* __restrict__ lens) {
  __shared__ __attribute__((aligned(16))) unsigned short As[2][4096];
  __shared__ __attribute__((aligned(16))) unsigned short Bs[2][4096];
  const int id = blockIdx.x + (blockIdx.y << 3);  // 0..255
  const int rest = id >> 3;
  const int my = (id & 7) + ((rest & 3) << 3);    // m-block 0..31
  const int nx = rest >> 2;                       // n-block 0..7
  const int tid = threadIdx.x;
  const int lane = tid & 63, w = tid >> 6;
  const int lq = lane & 15, lg = lane >> 4;
  const int m0 = my * 128, n0 = nx * 128;
  const int wm = (w & 1) * 64, wn = (w >> 1) * 64;
  const int b = my >> 3;

  if (((my & 7) << 7) >= (int)lens[b]) {
    // fully-masked q-rows: output is exactly zero; skip the K-loop
#pragma unroll
    for (int mi = 0; mi < 4; ++mi) {
      const int t0 = (m0 + wm + mi * 16 + lg * 4) & 1023;
      const f4v z = {};
#pragma unroll
      for (int ni = 0; ni < 4; ++ni) {
        const int n = n0 + wn + ni * 16 + lq;
        *(f4v*)&Cout[(size_t)b * 1024 * 1024 + (size_t)n * 1024 + t0] = z;
      }
    }
    return;
  }

  const int srow = tid >> 2;
  const int scol = ((tid & 3) * 8) ^ ((srow & 3) << 3);
  const unsigned short* Ap = A + (size_t)(m0 + srow) * 1024 + scol;
  const unsigned short* Bp = Bt + (size_t)(n0 + srow) * 1024 + scol;
  const int rc = (lg * 8) ^ ((lq & 3) << 3);
  f4v acc[4][4] = {};

  STAGE_G(0, 0);
  STAGE_G(1, 1);

  for (int kt = 0; kt < 32; ++kt) {
    const int cur = kt & 1;
    if (kt < 31) {
      asm volatile("s_waitcnt vmcnt(4)" ::: "memory");
    } else {
      asm volatile("s_waitcnt vmcnt(0)" ::: "memory");
    }
    __builtin_amdgcn_s_barrier();
    s8v af[4], bfr[4];
#pragma unroll
    for (int i = 0; i < 4; ++i)
      af[i] = *(const s8v*)&As[cur][(wm + i * 16 + lq) * 32 + rc];
#pragma unroll
    for (int i = 0; i < 4; ++i)
      bfr[i] = *(const s8v*)&Bs[cur][(wn + i * 16 + lq) * 32 + rc];
#pragma unroll
    for (int mi = 0; mi < 4; ++mi)
#pragma unroll
      for (int ni = 0; ni < 4; ++ni)
        acc[mi][ni] = __builtin_amdgcn_mfma_f32_16x16x32_bf16(af[mi], bfr[ni], acc[mi][ni], 0, 0, 0);
    __builtin_amdgcn_s_barrier();
    if (kt + 2 < 32) STAGE_G(cur, kt + 2);
  }

  float bv4[4];
#pragma unroll
  for (int ni = 0; ni < 4; ++ni) bv4[ni] = bias[n0 + wn + ni * 16 + lq];
#pragma unroll
  for (int mi = 0; mi < 4; ++mi) {
    const int mbase = m0 + wm + mi * 16 + lg * 4;
    const int t0 = mbase & 1023;
#pragma unroll
    for (int ni = 0; ni < 4; ++ni) {
      const int n = n0 + wn + ni * 16 + lq;
      f4v pk;
#pragma unroll
      for (int rr = 0; rr < 4; ++rr) {
        float v = acc[mi][ni][rr] + bv4[ni];
        v *= (float)xmask[b * 1024 + t0 + rr];
        pk[rr] = v;
      }
      *(f4v*)&Cout[(size_t)b * 1024 * 1024 + (size_t)n * 1024 + t0] = pk;
    }
  }
}

// ---------------- flash attention; 8 waves / 128 q-rows per block; KVBLK=64 double-buffered
// (proven R11 structure: 16x16 MFMA, LDS P-bounce, VGPR 40 -> 8 waves/SIMD)
__global__ __launch_bounds__(512) void attn_kernel(
    const unsigned short* __restrict__ Q, const unsigned short* __restrict__ K,
    const unsigned short* __restrict__ Vt, const float* __restrict__ lens,
    unsigned short* __restrict__ Aout) {
  __shared__ __attribute__((aligned(16))) unsigned short Ks[2][4096];
  __shared__ __attribute__((aligned(16))) unsigned short Vs[2][4096];
  __shared__ __attribute__((aligned(16))) unsigned short Plds[8][16][72];
  const int tid = threadIdx.x;
  const int lane = tid & 63, w = tid >> 6;
  const int lq = lane & 15, lg = lane >> 4;
  // XCD swizzle: the 8 q-blocks sharing one (b,h) K/V panel land on the same XCD
  const int id = blockIdx.x + (blockIdx.y << 3);  // 0..511
  const int bh = (id & 7) + (((id >> 3) & 7) << 3);
  const int qblk = id >> 6;
  const int b = bh >> 4, h = bh & 15;
  const int lenq = (int)lens[b];
  if (qblk * 128 >= lenq) return;  // fully-masked q-tile (output masked downstream)
  const int lenk = (int)lens[4 + b];
  const int nkt = (lenk + 63) >> 6;
  const int qrow = qblk * 128 + w * 16;
  const unsigned short* Qp = Q + ((size_t)bh * 1024 + qrow) * 64;
  const unsigned short* Kp = K + (size_t)bh * 65536;
  const unsigned short* Vp = Vt + (size_t)bh * 65536;
  const s8v qf0 = *(const s8v*)&Qp[lq * 64 + lg * 8];
  const s8v qf1 = *(const s8v*)&Qp[lq * 64 + 32 + lg * 8];
  const int r0 = tid >> 3;
  const int c0x = ((tid & 7) * 8) ^ ((r0 & 7) << 3);
  const int cswz = (lq & 7) << 3;

  gll16(&Kp[(size_t)r0 * 64 + c0x], &Ks[0][tid * 8]);
  gll16(&Vp[(size_t)r0 * 1024 + c0x], &Vs[0][tid * 8]);
  __syncthreads();

  float m_run = -1e30f, s_run = 0.0f;
  f4v ot[4] = {};
  for (int kt = 0; kt < nkt; ++kt) {
    const int p = kt & 1;
    if (kt + 1 < nkt) {  // prefetch next tile
      const int kn = (kt + 1) * 64;
      gll16(&Kp[(size_t)(kn + r0) * 64 + c0x], &Ks[p ^ 1][tid * 8]);
      gll16(&Vp[(size_t)r0 * 1024 + kn + c0x], &Vs[p ^ 1][tid * 8]);
    }
    const int k0 = kt * 64;
    const bool full = (k0 + 64 <= lenk);  // wave-uniform: skip key-mask compares
    float pvv[16];
    float tmax = -1e30f;
    __builtin_amdgcn_s_setprio(1);
#pragma unroll
    for (int kk = 0; kk < 4; ++kk) {
      const int krow = kk * 16 + lq;
      const s8v a0 = *(const s8v*)&Ks[p][krow * 64 + ((lg * 8) ^ cswz)];
      const s8v a1 = *(const s8v*)&Ks[p][krow * 64 + ((32 + lg * 8) ^ cswz)];
      f4v s = {};
      s = __builtin_amdgcn_mfma_f32_16x16x32_bf16(a0, qf0, s, 0, 0, 0);
      s = __builtin_amdgcn_mfma_f32_16x16x32_bf16(a1, qf1, s, 0, 0, 0);
#pragma unroll
      for (int rr = 0; rr < 4; ++rr) {
        float v = s[rr];  // Q pre-scaled: already base-2 logits
        if (!full) {
          const int key = k0 + kk * 16 + lg * 4 + rr;
          if (key >= lenk) v = -1e30f;
        }
        pvv[kk * 4 + rr] = v;
        tmax = fmaxf(tmax, v);
      }
    }
    __builtin_amdgcn_s_setprio(0);
    tmax = fmaxf(tmax, __shfl_xor(tmax, 16));
    tmax = fmaxf(tmax, __shfl_xor(tmax, 32));
    if (__any(tmax > m_run + 8.0f)) {  // T13 defer-max: rescale only on real growth
      const float m_new = fmaxf(m_run, tmax);
      const float alpha = exp2f(m_run - m_new);
#pragma unroll
      for (int d = 0; d < 4; ++d)
#pragma unroll
        for (int j = 0; j < 4; ++j) ot[d][j] *= alpha;
      s_run *= alpha;
      m_run = m_new;
    }
    float psum = 0.0f;
#pragma unroll
    for (int kk = 0; kk < 4; ++kk) {
      const float e0 = exp2f(pvv[kk * 4 + 0] - m_run);
      const float e1 = exp2f(pvv[kk * 4 + 1] - m_run);
      const float e2 = exp2f(pvv[kk * 4 + 2] - m_run);
      const float e3 = exp2f(pvv[kk * 4 + 3] - m_run);
      psum += (e0 + e1) + (e2 + e3);
      u2v pw;
      pw[0] = cvtpk(e0, e1);
      pw[1] = cvtpk(e2, e3);
      *(u2v*)&Plds[w][lq][kk * 16 + lg * 4] = pw;
    }
    psum += __shfl_xor(psum, 16);
    psum += __shfl_xor(psum, 32);
    s_run += psum;
    const s8v pb0 = *(const s8v*)&Plds[w][lq][lg * 8];
    const s8v pb1 = *(const s8v*)&Plds[w][lq][32 + lg * 8];
    __builtin_amdgcn_s_setprio(1);
#pragma unroll
    for (int d = 0; d < 4; ++d) {
      const int vrow = d * 16 + lq;
      const s8v av0 = *(const s8v*)&Vs[p][vrow * 64 + ((lg * 8) ^ cswz)];
      const s8v av1 = *(const s8v*)&Vs[p][vrow * 64 + ((32 + lg * 8) ^ cswz)];
      ot[d] = __builtin_amdgcn_mfma_f32_16x16x32_bf16(av0, pb0, ot[d], 0, 0, 0);
      ot[d] = __builtin_amdgcn_mfma_f32_16x16x32_bf16(av1, pb1, ot[d], 0, 0, 0);
    }
    __builtin_amdgcn_s_setprio(0);
    if (kt + 1 < nkt) __syncthreads();
  }
  const float inv = 1.0f / s_run;
  const int t = qrow + lq;
  unsigned short* op = Aout + ((size_t)(b * 1024 + t)) * 1024 + h * 64;
#pragma unroll
  for (int d = 0; d < 4; ++d) {
    u4v oo;
#pragma unroll
    for (int rr = 0; rr < 4; ++rr) oo[rr] = f2bf(ot[d][rr] * inv);
    *(u4v*)&op[d * 16 + lg * 4] = oo;
  }
}

extern "C" void kernel_launch(void* const* d_in, const int* in_sizes, int n_in,
                              void* d_out, int out_size, void* d_ws, size_t ws_size,
                              hipStream_t stream) {
  const float* x   = (const float*)d_in[0];
  const float* ctx = (const float*)d_in[1];
  const int* xm = (const int*)d_in[2];
  const int* cm = (const int*)d_in[3];
  const float* Wq = (const float*)d_in[4];
  const float* bq = (const float*)d_in[5];
  const float* Wk = (const float*)d_in[6];
  const float* bk = (const float*)d_in[7];
  const float* Wv = (const float*)d_in[8];
  const float* bv = (const float*)d_in[9];
  const float* Wo = (const float*)d_in[10];
  const float* bo = (const float*)d_in[11];

  char* ws = (char*)d_ws;
  const size_t MB = 1024 * 1024;
  // xT dead after gemm_qkv (mode 0); AOb (written later by attn) aliases it.
  unsigned short* xT   = (unsigned short*)(ws);           // 8 MB
  unsigned short* AOb  = (unsigned short*)(ws);           // 8 MB (alias)
  unsigned short* ctxb = (unsigned short*)(ws + 8 * MB);  // 8 MB
  unsigned short* WqT  = (unsigned short*)(ws + 16 * MB); // 2 MB
  unsigned short* WkT  = (unsigned short*)(ws + 18 * MB); // 2 MB
  unsigned short* WvT  = (unsigned short*)(ws + 20 * MB); // 2 MB
  unsigned short* WoT  = (unsigned short*)(ws + 22 * MB); // 2 MB
  unsigned short* Qb   = (unsigned short*)(ws + 24 * MB); // 8 MB
  unsigned short* Kb   = (unsigned short*)(ws + 32 * MB); // 8 MB
  unsigned short* Vtb  = (unsigned short*)(ws + 40 * MB); // 8 MB
  float* lens          = (float*)(ws + 48 * MB);          // 32 B
  float2* rope         = (float2*)(ws + 49 * MB);         // 2 MB

  prep_kernel<<<dim3(32, 32, 14), 256, 0, stream>>>(x, ctx, Wq, Wk, Wv, Wo, xm, cm,
                                                    xT, ctxb, WqT, WkT, WvT, WoT, lens, rope);
  gemm_qkv_kernel<<<dim3(8, 32, 3), 256, 0, stream>>>(xT, ctxb, WqT, WkT, WvT,
                                                      bq, bk, bv, Qb, Kb, Vtb, rope, lens);
  attn_kernel<<<dim3(8, 64), 512, 0, stream>>>(Qb, Kb, Vtb, lens, AOb);
  gemm_o_kernel<<<dim3(8, 32), 256, 0, stream>>>(AOb, WoT, bo, (float*)d_out, xm, lens);
}